// Round 16
// baseline (155.773 us; speedup 1.0000x reference)
//
#include <hip/hip_runtime.h>
#include <hip/hip_bf16.h>
#include <math.h>

#define N_IN 85680
#define PRE_K 5000
#define POST_K 750
#define NW 79            // ceil(PRE_K/64) words
#define NPAD 5056        // NW*64
#define HSIZE 8192       // linear buckets over score-bit range (0.02, +inf)
#define CAND_MAX 8192
#define CONF_THR 0.02f
#define NMS_THR 0.4f
#define BITS_THR 0x3CA3D70Bu  // bits of smallest float > 0.02f

typedef unsigned int u32;
typedef unsigned long long u64;

// column-major triangle-packed mask: word k's segment starts at cbase(k), holds
// rows 64k..NPAD-1. cbase(k) = k*(5088 - 32k)  [u64 units]; cbase(79)=202240.
__device__ __forceinline__ int cbase(int k) { return k * (5088 - 32 * k); }

// opacity barrier: prevents FMA contraction so f32 math bit-matches numpy ref
__device__ __forceinline__ float opaquef(float x) { asm volatile("" : "+v"(x)); return x; }

// wave-uniform 64-bit broadcast via v_readlane (src lane must be uniform)
__device__ __forceinline__ u64 readlane64(u64 v, int l) {
    u32 lo = __builtin_amdgcn_readlane((u32)v, l);
    u32 hi = __builtin_amdgcn_readlane((u32)(v >> 32), l);
    return ((u64)hi << 32) | (u64)lo;
}

// monotone bucket of a score's float bits (score > CONF_THR guaranteed)
__device__ __forceinline__ u32 bucket_of(u32 bits) {
    u32 b = (bits - BITS_THR) >> 13;
    return b >= HSIZE ? (HSIZE - 1) : b;
}

// ---------------- histogram of valid score buckets (multi-block) ----------------
__global__ __launch_bounds__(256) void hist_kernel(const float2* __restrict__ conf2,
                                                   u32* __restrict__ hist) {
    __shared__ u32 h[HSIZE];
    for (int b = threadIdx.x; b < HSIZE; b += 256) h[b] = 0u;
    __syncthreads();
    int i = blockIdx.x * 256 + threadIdx.x;
    if (i < N_IN) {
        float s = conf2[i].y;
        if (s > CONF_THR) atomicAdd(&h[bucket_of(__float_as_uint(s))], 1u);
    }
    __syncthreads();
    for (int b = threadIdx.x; b < HSIZE; b += 256) {
        u32 v = h[b];
        if (v) atomicAdd(&hist[b], v);
    }
}

// ---------------- suffix-scan: bstart[b] = #keys in buckets > b; bsel ----------------
__global__ __launch_bounds__(1024) void scan_kernel(const u32* __restrict__ hist,
                                                    u32* __restrict__ bsel,
                                                    u32* __restrict__ bstart) {
    __shared__ u32 tot[1024];
    int c = threadIdx.x;
    u32 lh[8];
    u32 t = 0;
#pragma unroll
    for (int k = 0; k < 8; ++k) { lh[k] = hist[c * 8 + k]; t += lh[k]; }
    tot[c] = t;
    __syncthreads();
    for (int d = 1; d < 1024; d <<= 1) {
        u32 v = tot[c] + ((c + d < 1024) ? tot[c + d] : 0u);
        __syncthreads();
        tot[c] = v;
        __syncthreads();
    }
    u32 above = (c + 1 < 1024) ? tot[c + 1] : 0u;
    u32 s = above;
    for (int k = 7; k >= 0; --k) { bstart[c * 8 + k] = s; s += lh[k]; }
    if (above < PRE_K && above + t >= PRE_K) {
        u32 cum = above;
        for (int k = 7; k >= 0; --k) {
            cum += lh[k];
            if (cum >= PRE_K) { bsel[0] = (u32)(c * 8 + k); break; }
        }
    }
    if (c == 0 && tot[0] < PRE_K) bsel[0] = 0u;
}

// ---------------- scatter candidates bucket-grouped ----------------
__global__ __launch_bounds__(256) void compact_kernel(const float2* __restrict__ conf2,
                                                      const u32* __restrict__ bsel,
                                                      const u32* __restrict__ bstart,
                                                      u32* __restrict__ bfill,
                                                      u64* __restrict__ cand) {
    int i = blockIdx.x * 256 + threadIdx.x;
    if (i >= N_IN) return;
    float sc = conf2[i].y;
    if (!(sc > CONF_THR)) return;
    u32 bits = __float_as_uint(sc);
    u32 b = bucket_of(bits);
    if (b < bsel[0]) return;
    u32 pos = bstart[b] + atomicAdd(&bfill[b], 1u);
    if (pos < CAND_MAX) cand[pos] = ((u64)bits << 32) | (u64)(u32)(~(u32)i);
}

// ---------------- fused: exact rank within bucket + decode -> rows/boxes/validm ----------------
__global__ __launch_bounds__(256) void rankdec_kernel(const u64* __restrict__ cand,
                                                      const u32* __restrict__ bstart,
                                                      const u32* __restrict__ bfill,
                                                      const u32* __restrict__ bsel,
                                                      const float4* __restrict__ loc4,
                                                      const float4* __restrict__ pri4,
                                                      const float* __restrict__ lmk,
                                                      const int* __restrict__ imw,
                                                      const int* __restrict__ imh,
                                                      float4* __restrict__ rows4,
                                                      float4* __restrict__ boxes,
                                                      u64* __restrict__ validm) {
    u32 bs = bsel[0];
    u32 total = bstart[bs] + bfill[bs];
    if (total > CAND_MAX) total = CAND_MAX;
    float W = (float)(*imw), H = (float)(*imh);
    for (u32 s = blockIdx.x * blockDim.x + threadIdx.x; s < total;
         s += gridDim.x * blockDim.x) {
        u64 key = cand[s];
        u32 b = bucket_of((u32)(key >> 32));
        u32 st = bstart[b];
        u32 en = st + bfill[b];
        if (en > CAND_MAX) en = CAND_MAX;
        u32 r = st;
        for (u32 j = st; j < en; ++j) r += (cand[j] > key) ? 1u : 0u;
        if (r >= PRE_K) continue;
        u32 i = ~(u32)key;
        float score = __uint_as_float((u32)(key >> 32));
        float4 L = loc4[i];
        float4 P = pri4[i];
        float cx = P.x + opaquef((L.x * 0.1f) * P.z);
        float cy = P.y + opaquef((L.y * 0.1f) * P.w);
        float bw = P.z * (float)exp((double)(L.z * 0.2f));
        float bh = P.w * (float)exp((double)(L.w * 0.2f));
        float hw = opaquef(bw * 0.5f), hh = opaquef(bh * 0.5f);
        float x0 = (cx - hw) * W, y0 = (cy - hh) * H;
        float x1 = (cx + hw) * W, y1 = (cy + hh) * H;
        boxes[r] = make_float4(x0, y0, x1, y1);
        float lm[10];
#pragma unroll
        for (int p = 0; p < 5; ++p) {
            float2 q = ((const float2*)lmk)[(size_t)i * 5 + p];
            lm[2 * p]     = (P.x + opaquef((q.x * 0.1f) * P.z)) * W;
            lm[2 * p + 1] = (P.y + opaquef((q.y * 0.1f) * P.w)) * H;
        }
        float4* row = rows4 + (size_t)r * 4;
        row[0] = make_float4(x0, y0, x1, y1);
        row[1] = make_float4(score, lm[0], lm[1], lm[2]);
        row[2] = make_float4(lm[3], lm[4], lm[5], lm[6]);
        row[3] = make_float4(lm[7], lm[8], lm[9], 0.f);
        atomicOr(&validm[r >> 6], 1ull << (r & 63));
    }
}

// ---------------- symmetric IoU bitmask, column-major triangle-packed ----------------
__global__ __launch_bounds__(64) void mask_kernel(const float4* __restrict__ boxes,
                                                  u64* __restrict__ cmask) {
    int rem = blockIdx.x, rc = 0;
    while (rem >= rc + 1) { rem -= rc + 1; ++rc; }
    int cc = rem;
    __shared__ float4 cb[64];
    int t = threadIdx.x;
    cb[t] = boxes[cc * 64 + t];
    int i = rc * 64 + t;
    float4 bi = boxes[i];
    __syncthreads();
    float areai = (bi.z - bi.x) * (bi.w - bi.y);
    u64 word = 0ull;
#pragma unroll 4
    for (int k = 0; k < 64; ++k) {
        float4 bj = cb[k];
        float areaj = (bj.z - bj.x) * (bj.w - bj.y);
        float ltx = fmaxf(bi.x, bj.x), lty = fmaxf(bi.y, bj.y);
        float rbx = fminf(bi.z, bj.z), rby = fminf(bi.w, bj.w);
        float wx = fmaxf(rbx - ltx, 0.f), wy = fmaxf(rby - lty, 0.f);
        float inter = opaquef(wx * wy);
        float uni = fmaxf(areai + areaj - inter, 1e-12f);
        float iou = inter / uni;
        if (iou > NMS_THR) word |= (1ull << k);
    }
    if (i < PRE_K) cmask[(size_t)(cbase(cc) + (i - 64 * cc))] = word;
}

// guarded coalesced column load for the fold pipeline
#define LDCOL(j, base, cnt) \
    (((j) < (cnt)) ? cmask[(size_t)(cbase((base) + (j)) + r - 64 * ((base) + (j)))] : 0ull)

// tight busy-poll: wait until doneCnt >= need, or sentinel (> NW) -> dead
#define WAITCNT(need)                                                                  \
    for (;;) {                                                                         \
        u32 d_ = __hip_atomic_load(&doneCnt, __ATOMIC_ACQUIRE,                         \
                                   __HIP_MEMORY_SCOPE_WORKGROUP);                      \
        if (d_ > (u32)NW) { dead = true; break; }                                      \
        if (d_ >= (u32)(need)) break;                                                  \
    }

// ---------------- exact one-pass Gauss-Seidel NMS + fused scatter (1 block, 8 waves) ----
// v5: single monotone doneCnt + TIGHT BUSY-POLL (no s_sleep). R13-R15 all landed
// at 88-100us across three fold implementations -> the common cost was the
// s_sleep wake quantization on every handoff, not the folds. On-chain work per
// word is ~700cy (fold tail + ballot + ~15-step readlane chain + handshake);
// busy-poll makes the handoff ~1 poll interval. Dead waves must NOT store
// doneCnt (would regress the NW+9 sentinel).
__global__ __launch_bounds__(512) void reduce_scatter_kernel(const u64* __restrict__ cmask,
                                                             const u64* __restrict__ validm,
                                                             const float* __restrict__ rows,
                                                             float* __restrict__ out) {
    int tid = threadIdx.x;
    int g = tid >> 6, lane = tid & 63;
    __shared__ u64 keepAll[96];
    __shared__ u32 totKs[96];
    __shared__ u32 doneCnt;   // # finalized words; NW+9 = early-exit sentinel
    __shared__ u32 wpref[96];
    for (int k = tid; k < 96; k += 512) keepAll[k] = 0ull;
    if (tid == 0) doneCnt = 0u;
    __syncthreads();

    for (int s = 0; s < 10; ++s) {
        int w = s * 8 + g;
        if (w >= NW) break;
        int r = 64 * w + lane;
        u64 dreg = cmask[(size_t)(cbase(w) + lane)];   // UNMASKED (R13 fix)
        u64 dA = (w >= 1) ? cmask[(size_t)(cbase(w - 1) + r - 64 * (w - 1))] : 0ull;
        u64 dB = (w >= 2) ? cmask[(size_t)(cbase(w - 2) + r - 64 * (w - 2))] : 0ull;
        int wcap = (w >= 2) ? (w - 2) : 0;
        u64 sup = 0ull;
        bool dead = false;

        // pipelined fold over predecessor words [0, wcap): 8-wide double-buffered,
        // individually named registers (no arrays -> no scratch spill)
        int d0 = 0;
        int nb = wcap < 8 ? wcap : 8;
        u64 c0 = LDCOL(0, 0, nb), c1 = LDCOL(1, 0, nb), c2 = LDCOL(2, 0, nb), c3 = LDCOL(3, 0, nb);
        u64 c4 = LDCOL(4, 0, nb), c5 = LDCOL(5, 0, nb), c6 = LDCOL(6, 0, nb), c7 = LDCOL(7, 0, nb);
        while (d0 < wcap) {
            int d1 = d0 + nb;
            int nb2 = wcap - d1; if (nb2 > 8) nb2 = 8;
            u64 n0 = LDCOL(0, d1, nb2), n1 = LDCOL(1, d1, nb2), n2 = LDCOL(2, d1, nb2), n3 = LDCOL(3, d1, nb2);
            u64 n4 = LDCOL(4, d1, nb2), n5 = LDCOL(5, d1, nb2), n6 = LDCOL(6, d1, nb2), n7 = LDCOL(7, d1, nb2);
            WAITCNT(d0 + nb)   // words d0..d0+nb-1 final (<= w-3+1: precedes done[w-1])
            if (dead) break;
            if (0 < nb) sup |= keepAll[d0 + 0] & c0;
            if (1 < nb) sup |= keepAll[d0 + 1] & c1;
            if (2 < nb) sup |= keepAll[d0 + 2] & c2;
            if (3 < nb) sup |= keepAll[d0 + 3] & c3;
            if (4 < nb) sup |= keepAll[d0 + 4] & c4;
            if (5 < nb) sup |= keepAll[d0 + 5] & c5;
            if (6 < nb) sup |= keepAll[d0 + 6] & c6;
            if (7 < nb) sup |= keepAll[d0 + 7] & c7;
            c0 = n0; c1 = n1; c2 = n2; c3 = n3; c4 = n4; c5 = n5; c6 = n6; c7 = n7;
            d0 = d1; nb = nb2;
        }
        // final handshake: word w-1 final
        if (!dead && w > 0) { WAITCNT(w) }
        u64 keptw = 0ull;
        u32 tp = 0u;
        if (!dead) {
            tp = (w > 0) ? totKs[w - 1] : 0u;
            if (tp < POST_K) {
                if (w >= 2) sup |= keepAll[w - 2] & dB;
                if (w >= 1) sup |= keepAll[w - 1] & dA;
                u64 valw = validm[w];
                u64 cur = valw & ~__ballot(sup != 0ull);
                while (cur) {                  // wave-uniform chain (kept sparse)
                    int b = __ffsll((long long)cur) - 1;
                    keptw |= (1ull << b);
                    u64 roww = readlane64(dreg, b);  // row b = whom b suppresses
                    cur &= ~(roww | (1ull << b));
                }
            }
            if (lane == 0) {
                keepAll[w] = keptw;
                u32 tk = tp + (u32)__popcll(keptw);
                totKs[w] = tk;
                // release: sentinel if output fully determined, else w+1
                __hip_atomic_store(&doneCnt,
                                   (tk >= POST_K) ? (u32)(NW + 9) : (u32)(w + 1),
                                   __ATOMIC_RELEASE, __HIP_MEMORY_SCOPE_WORKGROUP);
            }
        }
        // dead waves: keepAll[w] stays 0 (rank-safe); do NOT touch doneCnt
    }
    __syncthreads();

    // word-prefix ranks
    if (tid == 0) {
        u32 s = 0;
        for (int w = 0; w < NW; ++w) { wpref[w] = s; s += (u32)__popcll(keepAll[w]); }
        wpref[NW] = s;
    }
    __syncthreads();
    u32 totk = wpref[NW]; if (totk > POST_K) totk = POST_K;
    for (int r = tid; r < PRE_K; r += 512) {
        int w = r >> 6, b = r & 63;
        u64 kw = keepAll[w];
        if ((kw >> b) & 1ull) {
            u32 rank = wpref[w] + (u32)__popcll(kw & ((1ull << b) - 1ull));
            if (rank < POST_K) {
                const float* src = rows + (size_t)r * 16;
                float* dst = out + (size_t)rank * 15;
#pragma unroll
                for (int c2 = 0; c2 < 15; ++c2) dst[c2] = src[c2];
            }
        }
    }
    for (int r = (int)totk + tid; r < POST_K; r += 512) {
        float* dst = out + (size_t)r * 15;
#pragma unroll
        for (int c2 = 0; c2 < 15; ++c2) dst[c2] = 0.f;
    }
}

extern "C" void kernel_launch(void* const* d_in, const int* in_sizes, int n_in,
                              void* d_out, int out_size, void* d_ws, size_t ws_size,
                              hipStream_t stream) {
    const float* loc = (const float*)d_in[0];
    const float2* conf2 = (const float2*)d_in[1];
    const float* lmk = (const float*)d_in[2];
    const float* pri = (const float*)d_in[3];
    const int* imw = (const int*)d_in[4];
    const int* imh = (const int*)d_in[5];
    float* out = (float*)d_out;
    char* base = (char*)d_ws;

    // workspace layout (bytes); total 2,184,768 (< 3,808,896 proven in R3-R15)
    u32* hist   = (u32*)(base + 0);         //  32768  [zeroed by memset]
    u32* bfill  = (u32*)(base + 32768);     //  32768  [zeroed]
    u32* bsel   = (u32*)(base + 65536);     //  64     [zeroed]
    u64* validm = (u64*)(base + 65600);     //  1024   [zeroed]  -> zero [0,66624)
    u32* bstart = (u32*)(base + 67648);     //  32768
    u64* cand   = (u64*)(base + 100416);    //  65536
    float* rows = (float*)(base + 165952);  //  320000 (5000 x 16)
    float4* boxes = (float4*)(base + 485952); // 80896 (NPAD x 16)
    u64* cmask  = (u64*)(base + 566848);    //  1617920 (202240 u64, triangle-packed)

    hipMemsetAsync(d_ws, 0, 66624, stream);

    hist_kernel<<<(N_IN + 255) / 256, 256, 0, stream>>>(conf2, hist);
    scan_kernel<<<1, 1024, 0, stream>>>(hist, bsel, bstart);
    compact_kernel<<<(N_IN + 255) / 256, 256, 0, stream>>>(conf2, bsel, bstart, bfill, cand);
    rankdec_kernel<<<24, 256, 0, stream>>>(cand, bstart, bfill, bsel, (const float4*)loc,
                                           (const float4*)pri, lmk, imw, imh,
                                           (float4*)rows, boxes, validm);
    mask_kernel<<<NW * (NW + 1) / 2, 64, 0, stream>>>(boxes, cmask);
    reduce_scatter_kernel<<<1, 512, 0, stream>>>(cmask, validm, rows, out);
}

// Round 17
// 142.368 us; speedup vs baseline: 1.0942x; 1.0942x over previous
//
#include <hip/hip_runtime.h>
#include <hip/hip_bf16.h>
#include <math.h>

#define N_IN 85680
#define PRE_K 5000
#define POST_K 750
#define NW 79            // ceil(PRE_K/64) words
#define NPAD 5056        // NW*64
#define HSIZE 8192       // linear buckets over score-bit range (0.02, +inf)
#define CAND_MAX 8192
#define CONF_THR 0.02f
#define NMS_THR 0.4f
#define BITS_THR 0x3CA3D70Bu  // bits of smallest float > 0.02f

typedef unsigned int u32;
typedef unsigned long long u64;

// column-major triangle-packed mask: word k's segment starts at cbase(k), holds
// rows 64k..NPAD-1. cbase(k) = k*(5088 - 32k)  [u64 units]; cbase(79)=202240.
__device__ __forceinline__ int cbase(int k) { return k * (5088 - 32 * k); }

// opacity barrier: prevents FMA contraction so f32 math bit-matches numpy ref
__device__ __forceinline__ float opaquef(float x) { asm volatile("" : "+v"(x)); return x; }

// wave-uniform 64-bit broadcast via v_readlane (src lane must be uniform)
__device__ __forceinline__ u64 readlane64(u64 v, int l) {
    u32 lo = __builtin_amdgcn_readlane((u32)v, l);
    u32 hi = __builtin_amdgcn_readlane((u32)(v >> 32), l);
    return ((u64)hi << 32) | (u64)lo;
}

// monotone bucket of a score's float bits (score > CONF_THR guaranteed)
__device__ __forceinline__ u32 bucket_of(u32 bits) {
    u32 b = (bits - BITS_THR) >> 13;
    return b >= HSIZE ? (HSIZE - 1) : b;
}

// ---------------- histogram of valid score buckets (multi-block) ----------------
__global__ __launch_bounds__(256) void hist_kernel(const float2* __restrict__ conf2,
                                                   u32* __restrict__ hist) {
    __shared__ u32 h[HSIZE];
    for (int b = threadIdx.x; b < HSIZE; b += 256) h[b] = 0u;
    __syncthreads();
    int i = blockIdx.x * 256 + threadIdx.x;
    if (i < N_IN) {
        float s = conf2[i].y;
        if (s > CONF_THR) atomicAdd(&h[bucket_of(__float_as_uint(s))], 1u);
    }
    __syncthreads();
    for (int b = threadIdx.x; b < HSIZE; b += 256) {
        u32 v = h[b];
        if (v) atomicAdd(&hist[b], v);
    }
}

// ---------------- suffix-scan: bstart[b] = #keys in buckets > b; bsel ----------------
__global__ __launch_bounds__(1024) void scan_kernel(const u32* __restrict__ hist,
                                                    u32* __restrict__ bsel,
                                                    u32* __restrict__ bstart) {
    __shared__ u32 tot[1024];
    int c = threadIdx.x;
    u32 lh[8];
    u32 t = 0;
#pragma unroll
    for (int k = 0; k < 8; ++k) { lh[k] = hist[c * 8 + k]; t += lh[k]; }
    tot[c] = t;
    __syncthreads();
    for (int d = 1; d < 1024; d <<= 1) {
        u32 v = tot[c] + ((c + d < 1024) ? tot[c + d] : 0u);
        __syncthreads();
        tot[c] = v;
        __syncthreads();
    }
    u32 above = (c + 1 < 1024) ? tot[c + 1] : 0u;
    u32 s = above;
    for (int k = 7; k >= 0; --k) { bstart[c * 8 + k] = s; s += lh[k]; }
    if (above < PRE_K && above + t >= PRE_K) {
        u32 cum = above;
        for (int k = 7; k >= 0; --k) {
            cum += lh[k];
            if (cum >= PRE_K) { bsel[0] = (u32)(c * 8 + k); break; }
        }
    }
    if (c == 0 && tot[0] < PRE_K) bsel[0] = 0u;
}

// ---------------- scatter candidates bucket-grouped ----------------
__global__ __launch_bounds__(256) void compact_kernel(const float2* __restrict__ conf2,
                                                      const u32* __restrict__ bsel,
                                                      const u32* __restrict__ bstart,
                                                      u32* __restrict__ bfill,
                                                      u64* __restrict__ cand) {
    int i = blockIdx.x * 256 + threadIdx.x;
    if (i >= N_IN) return;
    float sc = conf2[i].y;
    if (!(sc > CONF_THR)) return;
    u32 bits = __float_as_uint(sc);
    u32 b = bucket_of(bits);
    if (b < bsel[0]) return;
    u32 pos = bstart[b] + atomicAdd(&bfill[b], 1u);
    if (pos < CAND_MAX) cand[pos] = ((u64)bits << 32) | (u64)(u32)(~(u32)i);
}

// ---------------- fused: exact rank within bucket + decode -> rows/boxes/validm ----------------
__global__ __launch_bounds__(256) void rankdec_kernel(const u64* __restrict__ cand,
                                                      const u32* __restrict__ bstart,
                                                      const u32* __restrict__ bfill,
                                                      const u32* __restrict__ bsel,
                                                      const float4* __restrict__ loc4,
                                                      const float4* __restrict__ pri4,
                                                      const float* __restrict__ lmk,
                                                      const int* __restrict__ imw,
                                                      const int* __restrict__ imh,
                                                      float4* __restrict__ rows4,
                                                      float4* __restrict__ boxes,
                                                      u64* __restrict__ validm) {
    u32 bs = bsel[0];
    u32 total = bstart[bs] + bfill[bs];
    if (total > CAND_MAX) total = CAND_MAX;
    float W = (float)(*imw), H = (float)(*imh);
    for (u32 s = blockIdx.x * blockDim.x + threadIdx.x; s < total;
         s += gridDim.x * blockDim.x) {
        u64 key = cand[s];
        u32 b = bucket_of((u32)(key >> 32));
        u32 st = bstart[b];
        u32 en = st + bfill[b];
        if (en > CAND_MAX) en = CAND_MAX;
        u32 r = st;
        for (u32 j = st; j < en; ++j) r += (cand[j] > key) ? 1u : 0u;
        if (r >= PRE_K) continue;
        u32 i = ~(u32)key;
        float score = __uint_as_float((u32)(key >> 32));
        float4 L = loc4[i];
        float4 P = pri4[i];
        float cx = P.x + opaquef((L.x * 0.1f) * P.z);
        float cy = P.y + opaquef((L.y * 0.1f) * P.w);
        float bw = P.z * (float)exp((double)(L.z * 0.2f));
        float bh = P.w * (float)exp((double)(L.w * 0.2f));
        float hw = opaquef(bw * 0.5f), hh = opaquef(bh * 0.5f);
        float x0 = (cx - hw) * W, y0 = (cy - hh) * H;
        float x1 = (cx + hw) * W, y1 = (cy + hh) * H;
        boxes[r] = make_float4(x0, y0, x1, y1);
        float lm[10];
#pragma unroll
        for (int p = 0; p < 5; ++p) {
            float2 q = ((const float2*)lmk)[(size_t)i * 5 + p];
            lm[2 * p]     = (P.x + opaquef((q.x * 0.1f) * P.z)) * W;
            lm[2 * p + 1] = (P.y + opaquef((q.y * 0.1f) * P.w)) * H;
        }
        float4* row = rows4 + (size_t)r * 4;
        row[0] = make_float4(x0, y0, x1, y1);
        row[1] = make_float4(score, lm[0], lm[1], lm[2]);
        row[2] = make_float4(lm[3], lm[4], lm[5], lm[6]);
        row[3] = make_float4(lm[7], lm[8], lm[9], 0.f);
        atomicOr(&validm[r >> 6], 1ull << (r & 63));
    }
}

// ---------------- symmetric IoU bitmask, column-major triangle-packed ----------------
__global__ __launch_bounds__(64) void mask_kernel(const float4* __restrict__ boxes,
                                                  u64* __restrict__ cmask) {
    int rem = blockIdx.x, rc = 0;
    while (rem >= rc + 1) { rem -= rc + 1; ++rc; }
    int cc = rem;
    __shared__ float4 cb[64];
    int t = threadIdx.x;
    cb[t] = boxes[cc * 64 + t];
    int i = rc * 64 + t;
    float4 bi = boxes[i];
    __syncthreads();
    float areai = (bi.z - bi.x) * (bi.w - bi.y);
    u64 word = 0ull;
#pragma unroll 4
    for (int k = 0; k < 64; ++k) {
        float4 bj = cb[k];
        float areaj = (bj.z - bj.x) * (bj.w - bj.y);
        float ltx = fmaxf(bi.x, bj.x), lty = fmaxf(bi.y, bj.y);
        float rbx = fminf(bi.z, bj.z), rby = fminf(bi.w, bj.w);
        float wx = fmaxf(rbx - ltx, 0.f), wy = fmaxf(rby - lty, 0.f);
        float inter = opaquef(wx * wy);
        float uni = fmaxf(areai + areaj - inter, 1e-12f);
        float iou = inter / uni;
        if (iou > NMS_THR) word |= (1ull << k);
    }
    if (i < PRE_K) cmask[(size_t)(cbase(cc) + (i - 64 * cc))] = word;
}

// guarded coalesced column load for the fold pipeline
#define LDCOL(j, base, cnt) \
    (((j) < (cnt)) ? cmask[(size_t)(cbase((base) + (j)) + r - 64 * ((base) + (j)))] : 0ull)

// tight busy-poll on RELAXED atomic (no acquire fence: plain ds_read per poll).
// Correctness: writer orders keepAll/totKs stores before the flag store with an
// explicit lgkmcnt(0); LDS is a single per-CU memory, so once the flag value is
// observed the earlier LDS writes are visible. Compiler barrier after the loop
// stops LLVM hoisting keepAll reads above the poll.
#define WAITCNT(need)                                                                  \
    for (;;) {                                                                         \
        u32 d_ = __hip_atomic_load(&doneCnt, __ATOMIC_RELAXED,                         \
                                   __HIP_MEMORY_SCOPE_WORKGROUP);                      \
        if (d_ > (u32)NW) { dead = true; break; }                                      \
        if (d_ >= (u32)(need)) break;                                                  \
    }                                                                                  \
    asm volatile("" ::: "memory");

// ---------------- exact one-pass Gauss-Seidel NMS + fused scatter (1 block, 8 waves) ----
// v6: RELAXED handshake. R13-R16 showed the cost is invariant to fold structure,
// spill, and sleep-vs-busy — the common term was the ACQUIRE/RELEASE atomics:
// a workgroup release store emits s_waitcnt vmcnt(0) before ds_write, and the
// compiler pipelines the NEXT iteration's global prefetches above it, so every
// release drains ~an L2 latency; the acquire similarly blocks hoisting validm.
// Fix: plain-store + lgkmcnt(0) + relaxed flag (writer), relaxed poll (reader),
// and validm[w] preloaded at iteration top (off the post-handshake path).
__global__ __launch_bounds__(512) void reduce_scatter_kernel(const u64* __restrict__ cmask,
                                                             const u64* __restrict__ validm,
                                                             const float* __restrict__ rows,
                                                             float* __restrict__ out) {
    int tid = threadIdx.x;
    int g = tid >> 6, lane = tid & 63;
    __shared__ u64 keepAll[96];
    __shared__ u32 totKs[96];
    __shared__ u32 doneCnt;   // # finalized words; NW+9 = early-exit sentinel
    __shared__ u32 wpref[96];
    for (int k = tid; k < 96; k += 512) keepAll[k] = 0ull;
    if (tid == 0) doneCnt = 0u;
    __syncthreads();

    for (int s = 0; s < 10; ++s) {
        int w = s * 8 + g;
        if (w >= NW) break;
        int r = 64 * w + lane;
        u64 dreg = cmask[(size_t)(cbase(w) + lane)];   // UNMASKED (R13 fix)
        u64 dA = (w >= 1) ? cmask[(size_t)(cbase(w - 1) + r - 64 * (w - 1))] : 0ull;
        u64 dB = (w >= 2) ? cmask[(size_t)(cbase(w - 2) + r - 64 * (w - 2))] : 0ull;
        u64 valw = validm[w];                          // static: preload before waits
        int wcap = (w >= 2) ? (w - 2) : 0;
        u64 sup = 0ull;
        bool dead = false;

        // pipelined fold over predecessor words [0, wcap): 8-wide double-buffered,
        // individually named registers (no arrays -> no scratch spill)
        int d0 = 0;
        int nb = wcap < 8 ? wcap : 8;
        u64 c0 = LDCOL(0, 0, nb), c1 = LDCOL(1, 0, nb), c2 = LDCOL(2, 0, nb), c3 = LDCOL(3, 0, nb);
        u64 c4 = LDCOL(4, 0, nb), c5 = LDCOL(5, 0, nb), c6 = LDCOL(6, 0, nb), c7 = LDCOL(7, 0, nb);
        while (d0 < wcap) {
            int d1 = d0 + nb;
            int nb2 = wcap - d1; if (nb2 > 8) nb2 = 8;
            u64 n0 = LDCOL(0, d1, nb2), n1 = LDCOL(1, d1, nb2), n2 = LDCOL(2, d1, nb2), n3 = LDCOL(3, d1, nb2);
            u64 n4 = LDCOL(4, d1, nb2), n5 = LDCOL(5, d1, nb2), n6 = LDCOL(6, d1, nb2), n7 = LDCOL(7, d1, nb2);
            WAITCNT(d0 + nb)   // words d0..d0+nb-1 final
            if (dead) break;
            if (0 < nb) sup |= keepAll[d0 + 0] & c0;
            if (1 < nb) sup |= keepAll[d0 + 1] & c1;
            if (2 < nb) sup |= keepAll[d0 + 2] & c2;
            if (3 < nb) sup |= keepAll[d0 + 3] & c3;
            if (4 < nb) sup |= keepAll[d0 + 4] & c4;
            if (5 < nb) sup |= keepAll[d0 + 5] & c5;
            if (6 < nb) sup |= keepAll[d0 + 6] & c6;
            if (7 < nb) sup |= keepAll[d0 + 7] & c7;
            c0 = n0; c1 = n1; c2 = n2; c3 = n3; c4 = n4; c5 = n5; c6 = n6; c7 = n7;
            d0 = d1; nb = nb2;
        }
        // final handshake: word w-1 final
        if (!dead && w > 0) { WAITCNT(w) }
        u64 keptw = 0ull;
        u32 tp = 0u;
        if (!dead) {
            tp = (w > 0) ? totKs[w - 1] : 0u;
            if (tp < POST_K) {
                if (w >= 2) sup |= keepAll[w - 2] & dB;
                if (w >= 1) sup |= keepAll[w - 1] & dA;
                u64 cur = valw & ~__ballot(sup != 0ull);
                while (cur) {                  // wave-uniform chain (kept sparse)
                    int b = __ffsll((long long)cur) - 1;
                    keptw |= (1ull << b);
                    u64 roww = readlane64(dreg, b);  // row b = whom b suppresses
                    cur &= ~(roww | (1ull << b));
                }
            }
            if (lane == 0) {
                u32 tk = tp + (u32)__popcll(keptw);
                keepAll[w] = keptw;            // plain LDS stores...
                totKs[w] = tk;
                // ...ordered before the flag by lgkmcnt(0) (LDS-only, cheap; no vmcnt)
                asm volatile("s_waitcnt lgkmcnt(0)" ::: "memory");
                __hip_atomic_store(&doneCnt,
                                   (tk >= POST_K) ? (u32)(NW + 9) : (u32)(w + 1),
                                   __ATOMIC_RELAXED, __HIP_MEMORY_SCOPE_WORKGROUP);
            }
        }
        // dead waves: keepAll[w] stays 0 (rank-safe); do NOT touch doneCnt
    }
    __syncthreads();

    // word-prefix ranks
    if (tid == 0) {
        u32 s = 0;
        for (int w = 0; w < NW; ++w) { wpref[w] = s; s += (u32)__popcll(keepAll[w]); }
        wpref[NW] = s;
    }
    __syncthreads();
    u32 totk = wpref[NW]; if (totk > POST_K) totk = POST_K;
    for (int r = tid; r < PRE_K; r += 512) {
        int w = r >> 6, b = r & 63;
        u64 kw = keepAll[w];
        if ((kw >> b) & 1ull) {
            u32 rank = wpref[w] + (u32)__popcll(kw & ((1ull << b) - 1ull));
            if (rank < POST_K) {
                const float* src = rows + (size_t)r * 16;
                float* dst = out + (size_t)rank * 15;
#pragma unroll
                for (int c2 = 0; c2 < 15; ++c2) dst[c2] = src[c2];
            }
        }
    }
    for (int r = (int)totk + tid; r < POST_K; r += 512) {
        float* dst = out + (size_t)r * 15;
#pragma unroll
        for (int c2 = 0; c2 < 15; ++c2) dst[c2] = 0.f;
    }
}

extern "C" void kernel_launch(void* const* d_in, const int* in_sizes, int n_in,
                              void* d_out, int out_size, void* d_ws, size_t ws_size,
                              hipStream_t stream) {
    const float* loc = (const float*)d_in[0];
    const float2* conf2 = (const float2*)d_in[1];
    const float* lmk = (const float*)d_in[2];
    const float* pri = (const float*)d_in[3];
    const int* imw = (const int*)d_in[4];
    const int* imh = (const int*)d_in[5];
    float* out = (float*)d_out;
    char* base = (char*)d_ws;

    // workspace layout (bytes); total 2,184,768 (< 3,808,896 proven in R3-R16)
    u32* hist   = (u32*)(base + 0);         //  32768  [zeroed by memset]
    u32* bfill  = (u32*)(base + 32768);     //  32768  [zeroed]
    u32* bsel   = (u32*)(base + 65536);     //  64     [zeroed]
    u64* validm = (u64*)(base + 65600);     //  1024   [zeroed]  -> zero [0,66624)
    u32* bstart = (u32*)(base + 67648);     //  32768
    u64* cand   = (u64*)(base + 100416);    //  65536
    float* rows = (float*)(base + 165952);  //  320000 (5000 x 16)
    float4* boxes = (float4*)(base + 485952); // 80896 (NPAD x 16)
    u64* cmask  = (u64*)(base + 566848);    //  1617920 (202240 u64, triangle-packed)

    hipMemsetAsync(d_ws, 0, 66624, stream);

    hist_kernel<<<(N_IN + 255) / 256, 256, 0, stream>>>(conf2, hist);
    scan_kernel<<<1, 1024, 0, stream>>>(hist, bsel, bstart);
    compact_kernel<<<(N_IN + 255) / 256, 256, 0, stream>>>(conf2, bsel, bstart, bfill, cand);
    rankdec_kernel<<<24, 256, 0, stream>>>(cand, bstart, bfill, bsel, (const float4*)loc,
                                           (const float4*)pri, lmk, imw, imh,
                                           (float4*)rows, boxes, validm);
    mask_kernel<<<NW * (NW + 1) / 2, 64, 0, stream>>>(boxes, cmask);
    reduce_scatter_kernel<<<1, 512, 0, stream>>>(cmask, validm, rows, out);
}